// Round 12
// baseline (391.173 us; speedup 1.0000x reference)
//
#include <hip/hip_runtime.h>
#include <math.h>

static constexpr int N_NODES = 100000;
static constexpr int NNZ     = 1600000;
static constexpr int CFB     = 8192;
static constexpr int NBUCK   = (N_NODES + 63) / 64;      // 1563 row-buckets
static constexpr int N4      = N_NODES * 128 / 4;        // 3.2M float4 groups
static constexpr int NCHUNK  = 512;                      // edge chunks
static constexpr int EPC     = NNZ / NCHUNK;             // 3125 edges/chunk
static constexpr int NE      = NBUCK * NCHUNK;           // 800256 matrix entries

// packed transposed-W bf16 buffer offsets (elements)
static constexpr int WOF_10 = 0;                         // W1_0t [128][128]
static constexpr int WOF_20 = 16384;                     // W2_0t [128][128]
static constexpr int WOF_11 = 32768;                     // W1_1t [64][128]
static constexpr int WOF_21 = 40960;                     // W2_1t [64][128]
static constexpr int WOF_12 = 49152;                     // W1_2t [32][64]
static constexpr int WOF_22 = 51200;                     // W2_2t [32][64]
static constexpr int WTOT   = 53248;

typedef short bf16x8 __attribute__((ext_vector_type(8)));
typedef float f32x4  __attribute__((ext_vector_type(4)));
typedef float f32x2  __attribute__((ext_vector_type(2)));

__device__ __forceinline__ float lrelu(float x) { return x >= 0.0f ? x : 0.01f * x; }

__device__ __forceinline__ unsigned short f2bf(float x) {
  unsigned u = __float_as_uint(x);
  u += 0x7FFFu + ((u >> 16) & 1u);          // round-to-nearest-even
  return (unsigned short)(u >> 16);
}
__device__ __forceinline__ float bf2f(unsigned short h) {
  return __uint_as_float(((unsigned)h) << 16);
}
__device__ __forceinline__ unsigned pack2(float x, float y) {
  return (unsigned)f2bf(x) | ((unsigned)f2bf(y) << 16);
}

// ---- fused: chunk histogram + f32->bf16/fp8 convert + W transpose ----------
__global__ __launch_bounds__(256)
void cvt_fused(const float* __restrict__ embed, unsigned short* __restrict__ e0,
               unsigned char* __restrict__ q0,
               const float* __restrict__ W1_0, const float* __restrict__ W2_0,
               const float* __restrict__ W1_1, const float* __restrict__ W2_1,
               const float* __restrict__ W1_2, const float* __restrict__ W2_2,
               unsigned short* __restrict__ wt,
               const int* __restrict__ erows, int* __restrict__ cnt) {
  __shared__ int h[NBUCK];
  for (int b = threadIdx.x; b < NBUCK; b += 256) h[b] = 0;
  __syncthreads();
  const int c = blockIdx.x;
  const int e0i = c * EPC, e1i = e0i + EPC;
  for (int i = e0i + threadIdx.x; i < e1i; i += 256)
    atomicAdd(&h[erows[i] >> 6], 1);
  __syncthreads();
  for (int b = threadIdx.x; b < NBUCK; b += 256)
    cnt[c * NBUCK + b] = h[b];

  const int gid    = blockIdx.x * 256 + threadIdx.x;
  const int stride = NCHUNK * 256;
  // streaming bf16+fp8 convert of the embedding table
  for (int i = gid; i < N4; i += stride) {
    float4 v = reinterpret_cast<const float4*>(embed)[i];
    uint2 o; o.x = pack2(v.x, v.y); o.y = pack2(v.z, v.w);
    reinterpret_cast<uint2*>(e0)[i] = o;
    int q = __builtin_amdgcn_cvt_pk_fp8_f32(v.x * 1024.f, v.y * 1024.f, 0, false);
    q = __builtin_amdgcn_cvt_pk_fp8_f32(v.z * 1024.f, v.w * 1024.f, q, true);
    reinterpret_cast<unsigned*>(q0)[i] = (unsigned)q;
  }
  // W transpose+convert
  for (int i = gid; i < WTOT; i += stride) {
    const float* src; int off, din, dout;
    if      (i < WOF_20) { src = W1_0; off = WOF_10; din = 128; dout = 128; }
    else if (i < WOF_11) { src = W2_0; off = WOF_20; din = 128; dout = 128; }
    else if (i < WOF_21) { src = W1_1; off = WOF_11; din = 128; dout = 64;  }
    else if (i < WOF_12) { src = W2_1; off = WOF_21; din = 128; dout = 64;  }
    else if (i < WOF_22) { src = W1_2; off = WOF_12; din = 64;  dout = 32;  }
    else                 { src = W2_2; off = WOF_22; din = 64;  dout = 32;  }
    int j = i - off;
    int cc = j / din;
    int k  = j % din;
    wt[i] = f2bf(src[(size_t)k * dout + cc]);
  }
}

// --- per-bucket scan over its 512 chunk counts (strided, in place) ----------
__global__ __launch_bounds__(512)
void bucket_scan(int* __restrict__ cnt, int* __restrict__ btot) {
  __shared__ int s[NCHUNK];
  const int b = blockIdx.x;
  const int t = threadIdx.x;
  int v = cnt[(size_t)t * NBUCK + b];
  s[t] = v;
  __syncthreads();
  for (int off = 1; off < NCHUNK; off <<= 1) {
    int x = (t >= off) ? s[t - off] : 0;
    __syncthreads();
    s[t] += x;
    __syncthreads();
  }
  cnt[(size_t)t * NBUCK + b] = s[t] - v;   // exclusive within bucket
  if (t == NCHUNK - 1) btot[b] = s[t];
}

// ---- single-block exclusive scan of 1563 bucket totals -> bbase ------------
__global__ __launch_bounds__(256)
void base_scan(const int* __restrict__ btot, int* __restrict__ bbase) {
  __shared__ int tsum[256];
  const int t = threadIdx.x;
  int loc[8];
  int s = 0;
  #pragma unroll
  for (int j = 0; j < 8; ++j) {
    int idx = t * 8 + j;
    int v = (idx < NBUCK) ? btot[idx] : 0;
    loc[j] = s; s += v;
  }
  tsum[t] = s;
  __syncthreads();
  for (int off = 1; off < 256; off <<= 1) {
    int v = (t >= off) ? tsum[t - off] : 0;
    __syncthreads();
    tsum[t] += v;
    __syncthreads();
  }
  int base = (t == 0) ? 0 : tsum[t - 1];
  #pragma unroll
  for (int j = 0; j < 8; ++j) {
    int idx = t * 8 + j;
    if (idx < NBUCK) bbase[idx] = base + loc[j];
  }
  if (t == 0) bbase[NBUCK] = NNZ;
}

// ------- scatter into bucket regions (LDS cursors, coalescing runs) ---------
__global__ __launch_bounds__(256)
void scatter_bucket(const int* __restrict__ erows, const int* __restrict__ ecols,
                    const float* __restrict__ evals, const int* __restrict__ cnt,
                    const int* __restrict__ bbase, uint2* __restrict__ spackA) {
  __shared__ int cur[NBUCK];
  const int c = blockIdx.x;
  for (int b = threadIdx.x; b < NBUCK; b += 256)
    cur[b] = bbase[b] + cnt[c * NBUCK + b];
  __syncthreads();
  const int e0 = c * EPC, e1 = e0 + EPC;
  for (int i = e0 + threadIdx.x; i < e1; i += 256) {
    int r = erows[i];
    int p = atomicAdd(&cur[r >> 6], 1);
    uint2 rec;
    rec.x = (unsigned)ecols[i] | ((unsigned)(r & 63) << 17);
    rec.y = __float_as_uint(evals[i]);
    spackA[p] = rec;
  }
}

// -- in-bucket counting sort by (rowlow, col>>10): 13-bit key, 8192 bins -----
// Produces row-sorted AND col-ordered-within-row records + row_ptr.
__global__ __launch_bounds__(256)
void bucket_sort(const int* __restrict__ bbase, const uint2* __restrict__ spackA,
                 uint2* __restrict__ spackB, int* __restrict__ row_ptr) {
  __shared__ int hist[8192];
  __shared__ int tsum[256];
  const int b = blockIdx.x;
  const int t = threadIdx.x;
  const int j0 = bbase[b], j1 = bbase[b + 1];
  #pragma unroll
  for (int j = 0; j < 32; ++j) hist[t * 32 + j] = 0;
  __syncthreads();
  for (int k = j0 + t; k < j1; k += 256) {
    unsigned x = spackA[k].x;
    int key = (int)(((x >> 17) & 63) << 7) | (int)((x & 0x1FFFF) >> 10);
    atomicAdd(&hist[key], 1);
  }
  __syncthreads();
  // exclusive scan of 8192 bins: per-thread 32-bin sum -> block scan -> rewrite
  int s = 0;
  #pragma unroll
  for (int j = 0; j < 32; ++j) s += hist[t * 32 + j];
  tsum[t] = s;
  __syncthreads();
  for (int off = 1; off < 256; off <<= 1) {
    int v = (t >= off) ? tsum[t - off] : 0;
    __syncthreads();
    tsum[t] += v;
    __syncthreads();
  }
  int run = tsum[t] - s;                   // exclusive base for this thread's bins
  #pragma unroll
  for (int j = 0; j < 32; ++j) {
    int v = hist[t * 32 + j];
    hist[t * 32 + j] = run;
    run += v;
  }
  __syncthreads();
  // row_ptr before cursors get destroyed
  if (t < 64) {
    int row = b * 64 + t;
    if (row < N_NODES) row_ptr[row] = j0 + hist[t * 128];
  }
  if (b == NBUCK - 1 && t == 0) row_ptr[N_NODES] = NNZ;
  __syncthreads();
  for (int k = j0 + t; k < j1; k += 256) {
    uint2 rec = spackA[k];
    unsigned x = rec.x;
    int key = (int)(((x >> 17) & 63) << 7) | (int)((x & 0x1FFFF) >> 10);
    int p = j0 + atomicAdd(&hist[key], 1);
    spackB[p] = rec;
  }
}

// ---------------- SpMM (CSR, fp8 gather): one wave per row ------------------
template<int DIN>
__global__ __launch_bounds__(256)
void spmm_fp8(const unsigned char* __restrict__ qtab, float inv_scale,
              const int* __restrict__ row_ptr,
              const uint2* __restrict__ spack,
              unsigned short* __restrict__ side) {
  int row  = blockIdx.x * 4 + (threadIdx.x >> 6);
  int lane = threadIdx.x & 63;
  if (row >= N_NODES) return;
  int j0 = row_ptr[row], j1 = row_ptr[row + 1];
  if constexpr (DIN == 128) {
    float ax = 0.f, ay = 0.f;
    #pragma unroll 8
    for (int j = j0; j < j1; ++j) {
      uint2 rec = spack[j];
      float v = __uint_as_float(rec.y);
      unsigned q = *reinterpret_cast<const unsigned short*>(
          qtab + (size_t)(rec.x & 0x1FFFF) * 128 + lane * 2);
      f32x2 xy = __builtin_amdgcn_cvt_pk_f32_fp8(q, false);
      ax += v * xy.x;  ay += v * xy.y;
    }
    *reinterpret_cast<unsigned*>(side + (size_t)row * 128 + lane * 2) =
        pack2(ax * inv_scale, ay * inv_scale);
  } else {
    float a = 0.f;
    #pragma unroll 8
    for (int j = j0; j < j1; ++j) {
      uint2 rec = spack[j];
      unsigned q = qtab[(size_t)(rec.x & 0x1FFFF) * DIN + lane];
      a += __uint_as_float(rec.y) * __builtin_amdgcn_cvt_f32_fp8(q, 0);
    }
    side[(size_t)row * DIN + lane] = f2bf(a * inv_scale);
  }
}

// -------- bi-interaction via MFMA: out = lrelu((e+s)W1+b1)+lrelu((e*s)W2+b2)
template<int DIN, int DOUT, int WM, int WN, int TPB, bool QOUT>
__global__ __launch_bounds__(256)
void bi_mfma(const unsigned short* __restrict__ ego,
             const unsigned short* __restrict__ side,
             const unsigned short* __restrict__ W1t, const float* __restrict__ b1,
             const unsigned short* __restrict__ W2t, const float* __restrict__ b2,
             unsigned short* __restrict__ out,
             unsigned char* __restrict__ outq, float qs) {
  static_assert(WM * WN == 4, "4 waves");
  constexpr int KFRAG = DIN / 32;
  constexpr int NCOLS = DOUT / WN;
  constexpr int NFRAG = NCOLS / 16;
  constexpr int MROWS = 32 / WM;
  constexpr int MFRAG = MROWS / 16;
  constexpr int CPR   = DIN / 8;
  constexpr int CHUNKS = 32 * CPR;

  __shared__ __align__(16) unsigned short lds1[32 * DIN];
  __shared__ __align__(16) unsigned short lds2[32 * DIN];

  const int tid  = threadIdx.x;
  const int wid  = tid >> 6;
  const int lane = tid & 63;
  const int n0   = (wid % WN) * NCOLS;
  const int mrow0 = (wid / WN) * MROWS;
  const int lr   = lane & 15;
  const int lk   = (lane >> 4) * 8;

  bf16x8 w1f[KFRAG][NFRAG], w2f[KFRAG][NFRAG];
  #pragma unroll
  for (int kf = 0; kf < KFRAG; ++kf)
    #pragma unroll
    for (int nf = 0; nf < NFRAG; ++nf) {
      int col = n0 + nf * 16 + lr;
      int kr  = kf * 32 + lk;
      w1f[kf][nf] = *reinterpret_cast<const bf16x8*>(W1t + (size_t)col * DIN + kr);
      w2f[kf][nf] = *reinterpret_cast<const bf16x8*>(W2t + (size_t)col * DIN + kr);
    }
  float b1v[NFRAG], b2v[NFRAG];
  #pragma unroll
  for (int nf = 0; nf < NFRAG; ++nf) {
    b1v[nf] = b1[n0 + nf * 16 + lr];
    b2v[nf] = b2[n0 + nf * 16 + lr];
  }

  for (int t = 0; t < TPB; ++t) {
    int row0 = (blockIdx.x * TPB + t) * 32;
    if (row0 >= N_NODES) break;
    __syncthreads();
    for (int ci = tid; ci < CHUNKS; ci += 256) {
      int r  = ci / CPR;
      int c8 = ci % CPR;
      size_t g = (size_t)(row0 + r) * DIN + c8 * 8;
      uint4 e4 = *reinterpret_cast<const uint4*>(ego + g);
      uint4 s4 = *reinterpret_cast<const uint4*>(side + g);
      uint4 h1v, h2v;
      {
        float ex, ey, sx, sy;
        ex = bf2f((unsigned short)(e4.x & 0xFFFFu)); ey = bf2f((unsigned short)(e4.x >> 16));
        sx = bf2f((unsigned short)(s4.x & 0xFFFFu)); sy = bf2f((unsigned short)(s4.x >> 16));
        h1v.x = pack2(ex + sx, ey + sy); h2v.x = pack2(ex * sx, ey * sy);
        ex = bf2f((unsigned short)(e4.y & 0xFFFFu)); ey = bf2f((unsigned short)(e4.y >> 16));
        sx = bf2f((unsigned short)(s4.y & 0xFFFFu)); sy = bf2f((unsigned short)(s4.y >> 16));
        h1v.y = pack2(ex + sx, ey + sy); h2v.y = pack2(ex * sx, ey * sy);
        ex = bf2f((unsigned short)(e4.z & 0xFFFFu)); ey = bf2f((unsigned short)(e4.z >> 16));
        sx = bf2f((unsigned short)(s4.z & 0xFFFFu)); sy = bf2f((unsigned short)(s4.z >> 16));
        h1v.z = pack2(ex + sx, ey + sy); h2v.z = pack2(ex * sx, ey * sy);
        ex = bf2f((unsigned short)(e4.w & 0xFFFFu)); ey = bf2f((unsigned short)(e4.w >> 16));
        sx = bf2f((unsigned short)(s4.w & 0xFFFFu)); sy = bf2f((unsigned short)(s4.w >> 16));
        h1v.w = pack2(ex + sx, ey + sy); h2v.w = pack2(ex * sx, ey * sy);
      }
      unsigned byte = ((unsigned)(r * DIN + c8 * 8)) * 2u;
      byte ^= (unsigned)((r & 7) << 4);
      *reinterpret_cast<uint4*>(reinterpret_cast<char*>(lds1) + byte) = h1v;
      *reinterpret_cast<uint4*>(reinterpret_cast<char*>(lds2) + byte) = h2v;
    }
    __syncthreads();

    f32x4 acc1[MFRAG][NFRAG], acc2[MFRAG][NFRAG];
    #pragma unroll
    for (int mf = 0; mf < MFRAG; ++mf)
      #pragma unroll
      for (int nf = 0; nf < NFRAG; ++nf) {
        acc1[mf][nf] = (f32x4)0.f;
        acc2[mf][nf] = (f32x4)0.f;
      }
    #pragma unroll
    for (int kf = 0; kf < KFRAG; ++kf) {
      bf16x8 a1[MFRAG], a2[MFRAG];
      #pragma unroll
      for (int mf = 0; mf < MFRAG; ++mf) {
        int r = mrow0 + mf * 16 + lr;
        unsigned byte = ((unsigned)(r * DIN + kf * 32 + lk)) * 2u;
        byte ^= (unsigned)((r & 7) << 4);
        a1[mf] = *reinterpret_cast<const bf16x8*>(reinterpret_cast<const char*>(lds1) + byte);
        a2[mf] = *reinterpret_cast<const bf16x8*>(reinterpret_cast<const char*>(lds2) + byte);
      }
      #pragma unroll
      for (int mf = 0; mf < MFRAG; ++mf)
        #pragma unroll
        for (int nf = 0; nf < NFRAG; ++nf) {
          acc1[mf][nf] = __builtin_amdgcn_mfma_f32_16x16x32_bf16(a1[mf], w1f[kf][nf], acc1[mf][nf], 0, 0, 0);
          acc2[mf][nf] = __builtin_amdgcn_mfma_f32_16x16x32_bf16(a2[mf], w2f[kf][nf], acc2[mf][nf], 0, 0, 0);
        }
    }

    #pragma unroll
    for (int mf = 0; mf < MFRAG; ++mf)
      #pragma unroll
      for (int nf = 0; nf < NFRAG; ++nf) {
        #pragma unroll
        for (int reg = 0; reg < 4; ++reg) {
          int r = row0 + mrow0 + mf * 16 + (lane >> 4) * 4 + reg;
          int c = n0 + nf * 16 + lr;
          float o = lrelu(acc1[mf][nf][reg] + b1v[nf]) + lrelu(acc2[mf][nf][reg] + b2v[nf]);
          out[(size_t)r * DOUT + c] = f2bf(o);
          if constexpr (QOUT) {
            float oq = o * qs;
            outq[(size_t)r * DOUT + c] =
                (unsigned char)(__builtin_amdgcn_cvt_pk_fp8_f32(oq, oq, 0, false) & 0xFF);
          }
        }
      }
  }
}

// -------- fused score pass over all 4 layer outputs -------------------------
__global__ __launch_bounds__(256)
void score_all(const float* __restrict__ emb0,
               const unsigned short* __restrict__ e1,
               const unsigned short* __restrict__ e2,
               const unsigned short* __restrict__ e3,
               const int* __restrict__ uid, const int* __restrict__ pid,
               const int* __restrict__ nid,
               float* __restrict__ pos, float* __restrict__ neg,
               float* __restrict__ l2) {
  int i = blockIdx.x * 4 + (threadIdx.x >> 6);
  int lane = threadIdx.x & 63;
  if (i >= CFB) return;
  const int ui = uid[i], pi = pid[i], gi = nid[i];
  float PS = 0.f, NS = 0.f, L2 = 0.f;

  {
    float up = 0, un = 0, uu = 0, pp = 0, nn = 0;
    for (int d = lane; d < 128; d += 64) {
      float a = emb0[(size_t)ui * 128 + d];
      float b = emb0[(size_t)pi * 128 + d];
      float c = emb0[(size_t)gi * 128 + d];
      up += a * b; un += a * c; uu += a * a; pp += b * b; nn += c * c;
    }
    #pragma unroll
    for (int off = 32; off > 0; off >>= 1) {
      up += __shfl_xor(up, off); un += __shfl_xor(un, off);
      uu += __shfl_xor(uu, off); pp += __shfl_xor(pp, off); nn += __shfl_xor(nn, off);
    }
    PS += up; NS += un; L2 += uu + pp + nn;
  }
  const unsigned short* tabs[3] = { e1, e2, e3 };
  const int dims[3] = { 128, 64, 32 };
  #pragma unroll
  for (int L = 0; L < 3; ++L) {
    const unsigned short* T = tabs[L];
    const int dim = dims[L];
    float up = 0, un = 0, uu = 0, pp = 0, nn = 0;
    for (int d = lane; d < dim; d += 64) {
      float a = bf2f(T[(size_t)ui * dim + d]);
      float b = bf2f(T[(size_t)pi * dim + d]);
      float c = bf2f(T[(size_t)gi * dim + d]);
      up += a * b; un += a * c; uu += a * a; pp += b * b; nn += c * c;
    }
    #pragma unroll
    for (int off = 32; off > 0; off >>= 1) {
      up += __shfl_xor(up, off); un += __shfl_xor(un, off);
      uu += __shfl_xor(uu, off); pp += __shfl_xor(pp, off); nn += __shfl_xor(nn, off);
    }
    float mu = fmaxf(sqrtf(uu), 1e-12f);
    float mp = fmaxf(sqrtf(pp), 1e-12f);
    float mn = fmaxf(sqrtf(nn), 1e-12f);
    PS += up / (mu * mp);
    NS += un / (mu * mn);
    L2 += uu / (mu * mu) + pp / (mp * mp) + nn / (mn * mn);
  }
  if (lane == 0) { pos[i] = PS; neg[i] = NS; l2[i] = L2; }
}

// ---------------------------- final loss reduce -----------------------------
__global__ __launch_bounds__(256)
void loss_kernel(const float* __restrict__ pos, const float* __restrict__ neg,
                 const float* __restrict__ l2, float* __restrict__ out) {
  __shared__ float s1[256];
  __shared__ float s2[256];
  int tid = threadIdx.x;
  float cf = 0.f, reg = 0.f;
  for (int i = tid; i < CFB; i += 256) {
    float x = pos[i] - neg[i];
    float sp = (x > 0.f) ? log1pf(expf(-x)) : (-x + log1pf(expf(x)));
    cf  += sp;
    reg += l2[i];
  }
  s1[tid] = cf; s2[tid] = reg;
  __syncthreads();
  for (int s = 128; s > 0; s >>= 1) {
    if (tid < s) { s1[tid] += s1[tid + s]; s2[tid] += s2[tid + s]; }
    __syncthreads();
  }
  if (tid == 0)
    out[0] = s1[0] / (float)CFB + 1e-5f * (0.5f * s2[0] / (float)CFB);
}

extern "C" void kernel_launch(void* const* d_in, const int* in_sizes, int n_in,
                              void* d_out, int out_size, void* d_ws, size_t ws_size,
                              hipStream_t stream) {
  const float* embed = (const float*)d_in[0];
  const float* W1_0 = (const float*)d_in[1];
  const float* b1_0 = (const float*)d_in[2];
  const float* W2_0 = (const float*)d_in[3];
  const float* b2_0 = (const float*)d_in[4];
  const float* W1_1 = (const float*)d_in[5];
  const float* b1_1 = (const float*)d_in[6];
  const float* W2_1 = (const float*)d_in[7];
  const float* b2_1 = (const float*)d_in[8];
  const float* W1_2 = (const float*)d_in[9];
  const float* b1_2 = (const float*)d_in[10];
  const float* W2_2 = (const float*)d_in[11];
  const float* b2_2 = (const float*)d_in[12];
  const int*   erows = (const int*)d_in[13];
  const int*   ecols = (const int*)d_in[14];
  const float* evals = (const float*)d_in[15];
  const int*   uid = (const int*)d_in[16];
  const int*   pid = (const int*)d_in[17];
  const int*   nid = (const int*)d_in[18];

  // ---------------- workspace layout (~146 MB) ----------------
  unsigned short* e0 = (unsigned short*)d_ws;               // N*128 bf16
  unsigned short* e1 = e0 + (size_t)N_NODES * 128;          // N*128
  unsigned short* e2 = e1 + (size_t)N_NODES * 128;          // N*64
  unsigned short* e3 = e2 + (size_t)N_NODES * 64;           // N*32
  unsigned short* sb = e3 + (size_t)N_NODES * 32;           // N*128 (side)
  unsigned char*  q0 = (unsigned char*)(sb + (size_t)N_NODES * 128);  // N*128 fp8
  unsigned char*  q2 = q0 + (size_t)N_NODES * 128;          // N*64 fp8
  unsigned short* wt = (unsigned short*)(q2 + (size_t)N_NODES * 64);  // WTOT bf16
  int*   cnt     = (int*)(wt + WTOT);                       // NE (chunk x bucket)
  int*   btot    = cnt + NE;                                // NBUCK
  int*   bbase   = btot + NBUCK;                            // NBUCK+1
  int*   row_ptr = bbase + NBUCK + 1;                       // N+1
  uint2* spackA  = (uint2*)(row_ptr + N_NODES + 2);         // NNZ (dead after build)
  uint2* spackB  = spackA + NNZ;                            // NNZ
  unsigned char* q1 = (unsigned char*)spackA;               // N*128 fp8 (aliases spackA)
  float* posb    = (float*)(spackB + NNZ);
  float* negb    = posb + CFB;
  float* l2b     = negb + CFB;

  // ---------------- fused prep + CSR build ----------------
  cvt_fused<<<NCHUNK, 256, 0, stream>>>(embed, e0, q0, W1_0, W2_0, W1_1, W2_1,
                                        W1_2, W2_2, wt, erows, cnt);
  bucket_scan<<<NBUCK, NCHUNK, 0, stream>>>(cnt, btot);
  base_scan<<<1, 256, 0, stream>>>(btot, bbase);
  scatter_bucket<<<NCHUNK, 256, 0, stream>>>(erows, ecols, evals, cnt, bbase, spackA);
  bucket_sort<<<NBUCK, 256, 0, stream>>>(bbase, spackA, spackB, row_ptr);

  constexpr int TPB = 5;
  constexpr int GB  = (N_NODES / 32 + TPB - 1) / TPB;

  // ---- layer 0: 128 -> 128 (gather fp8 q0, scale 1024) ----
  spmm_fp8<128><<<(N_NODES + 3) / 4, 256, 0, stream>>>(q0, 1.f / 1024.f, row_ptr, spackB, sb);
  bi_mfma<128, 128, 1, 4, TPB, true><<<GB, 256, 0, stream>>>(e0, sb, wt + WOF_10, b1_0, wt + WOF_20, b2_0, e1, q1, 64.f);

  // ---- layer 1: 128 -> 64 (gather fp8 q1, scale 64) ----
  spmm_fp8<128><<<(N_NODES + 3) / 4, 256, 0, stream>>>(q1, 1.f / 64.f, row_ptr, spackB, sb);
  bi_mfma<128, 64, 1, 4, TPB, true><<<GB, 256, 0, stream>>>(e1, sb, wt + WOF_11, b1_1, wt + WOF_21, b2_1, e2, q2, 64.f);

  // ---- layer 2: 64 -> 32 (gather fp8 q2, scale 64) ----
  spmm_fp8<64><<<(N_NODES + 3) / 4, 256, 0, stream>>>(q2, 1.f / 64.f, row_ptr, spackB, sb);
  bi_mfma<64, 32, 2, 2, TPB, false><<<GB, 256, 0, stream>>>(e2, sb, wt + WOF_12, b1_2, wt + WOF_22, b2_2, e3, (unsigned char*)nullptr, 0.f);

  // ---- fused scoring over all 4 layer outputs + loss ----
  score_all<<<CFB / 4, 256, 0, stream>>>(embed, e1, e2, e3, uid, pid, nid, posb, negb, l2b);
  loss_kernel<<<1, 256, 0, stream>>>(posb, negb, l2b, (float*)d_out);
}

// Round 13
// 375.986 us; speedup vs baseline: 1.0404x; 1.0404x over previous
//
#include <hip/hip_runtime.h>
#include <math.h>

static constexpr int N_NODES = 100000;
static constexpr int NNZ     = 1600000;
static constexpr int CFB     = 8192;
static constexpr int NBUCK   = (N_NODES + 63) / 64;      // 1563 row-buckets
static constexpr int N4      = N_NODES * 128 / 4;        // 3.2M float4 groups
static constexpr int NCHUNK  = 512;                      // edge chunks
static constexpr int EPC     = NNZ / NCHUNK;             // 3125 edges/chunk
static constexpr int NE      = NBUCK * NCHUNK;           // 800256 matrix entries

// packed transposed-W bf16 buffer offsets (elements)
static constexpr int WOF_10 = 0;                         // W1_0t [128][128]
static constexpr int WOF_20 = 16384;                     // W2_0t [128][128]
static constexpr int WOF_11 = 32768;                     // W1_1t [64][128]
static constexpr int WOF_21 = 40960;                     // W2_1t [64][128]
static constexpr int WOF_12 = 49152;                     // W1_2t [32][64]
static constexpr int WOF_22 = 51200;                     // W2_2t [32][64]
static constexpr int WTOT   = 53248;

typedef short bf16x8 __attribute__((ext_vector_type(8)));
typedef float f32x4  __attribute__((ext_vector_type(4)));
typedef float f32x2  __attribute__((ext_vector_type(2)));

__device__ __forceinline__ float lrelu(float x) { return x >= 0.0f ? x : 0.01f * x; }

__device__ __forceinline__ unsigned short f2bf(float x) {
  unsigned u = __float_as_uint(x);
  u += 0x7FFFu + ((u >> 16) & 1u);          // round-to-nearest-even
  return (unsigned short)(u >> 16);
}
__device__ __forceinline__ float bf2f(unsigned short h) {
  return __uint_as_float(((unsigned)h) << 16);
}
__device__ __forceinline__ unsigned pack2(float x, float y) {
  return (unsigned)f2bf(x) | ((unsigned)f2bf(y) << 16);
}

// ---- fused: chunk histogram + f32->bf16/fp8 convert + W transpose ----------
__global__ __launch_bounds__(256)
void cvt_fused(const float* __restrict__ embed, unsigned short* __restrict__ e0,
               unsigned char* __restrict__ q0,
               const float* __restrict__ W1_0, const float* __restrict__ W2_0,
               const float* __restrict__ W1_1, const float* __restrict__ W2_1,
               const float* __restrict__ W1_2, const float* __restrict__ W2_2,
               unsigned short* __restrict__ wt,
               const int* __restrict__ erows, int* __restrict__ cnt) {
  __shared__ int h[NBUCK];
  for (int b = threadIdx.x; b < NBUCK; b += 256) h[b] = 0;
  __syncthreads();
  const int c = blockIdx.x;
  const int e0i = c * EPC, e1i = e0i + EPC;
  for (int i = e0i + threadIdx.x; i < e1i; i += 256)
    atomicAdd(&h[erows[i] >> 6], 1);
  __syncthreads();
  for (int b = threadIdx.x; b < NBUCK; b += 256)
    cnt[c * NBUCK + b] = h[b];

  const int gid    = blockIdx.x * 256 + threadIdx.x;
  const int stride = NCHUNK * 256;
  for (int i = gid; i < N4; i += stride) {
    float4 v = reinterpret_cast<const float4*>(embed)[i];
    uint2 o; o.x = pack2(v.x, v.y); o.y = pack2(v.z, v.w);
    reinterpret_cast<uint2*>(e0)[i] = o;
    int q = __builtin_amdgcn_cvt_pk_fp8_f32(v.x * 1024.f, v.y * 1024.f, 0, false);
    q = __builtin_amdgcn_cvt_pk_fp8_f32(v.z * 1024.f, v.w * 1024.f, q, true);
    reinterpret_cast<unsigned*>(q0)[i] = (unsigned)q;
  }
  for (int i = gid; i < WTOT; i += stride) {
    const float* src; int off, din, dout;
    if      (i < WOF_20) { src = W1_0; off = WOF_10; din = 128; dout = 128; }
    else if (i < WOF_11) { src = W2_0; off = WOF_20; din = 128; dout = 128; }
    else if (i < WOF_21) { src = W1_1; off = WOF_11; din = 128; dout = 64;  }
    else if (i < WOF_12) { src = W2_1; off = WOF_21; din = 128; dout = 64;  }
    else if (i < WOF_22) { src = W1_2; off = WOF_12; din = 64;  dout = 32;  }
    else                 { src = W2_2; off = WOF_22; din = 64;  dout = 32;  }
    int j = i - off;
    int cc = j / din;
    int k  = j % din;
    wt[i] = f2bf(src[(size_t)k * dout + cc]);
  }
}

// --- per-bucket scan over its 512 chunk counts (strided, in place) ----------
__global__ __launch_bounds__(512)
void bucket_scan(int* __restrict__ cnt, int* __restrict__ btot) {
  __shared__ int s[NCHUNK];
  const int b = blockIdx.x;
  const int t = threadIdx.x;
  int v = cnt[(size_t)t * NBUCK + b];
  s[t] = v;
  __syncthreads();
  for (int off = 1; off < NCHUNK; off <<= 1) {
    int x = (t >= off) ? s[t - off] : 0;
    __syncthreads();
    s[t] += x;
    __syncthreads();
  }
  cnt[(size_t)t * NBUCK + b] = s[t] - v;   // exclusive within bucket
  if (t == NCHUNK - 1) btot[b] = s[t];
}

// ---- single-block exclusive scan of 1563 bucket totals -> bbase ------------
__global__ __launch_bounds__(256)
void base_scan(const int* __restrict__ btot, int* __restrict__ bbase) {
  __shared__ int tsum[256];
  const int t = threadIdx.x;
  int loc[8];
  int s = 0;
  #pragma unroll
  for (int j = 0; j < 8; ++j) {
    int idx = t * 8 + j;
    int v = (idx < NBUCK) ? btot[idx] : 0;
    loc[j] = s; s += v;
  }
  tsum[t] = s;
  __syncthreads();
  for (int off = 1; off < 256; off <<= 1) {
    int v = (t >= off) ? tsum[t - off] : 0;
    __syncthreads();
    tsum[t] += v;
    __syncthreads();
  }
  int base = (t == 0) ? 0 : tsum[t - 1];
  #pragma unroll
  for (int j = 0; j < 8; ++j) {
    int idx = t * 8 + j;
    if (idx < NBUCK) bbase[idx] = base + loc[j];
  }
  if (t == 0) bbase[NBUCK] = NNZ;
}

// ------- scatter into bucket regions (LDS cursors, coalescing runs) ---------
__global__ __launch_bounds__(256)
void scatter_bucket(const int* __restrict__ erows, const int* __restrict__ ecols,
                    const float* __restrict__ evals, const int* __restrict__ cnt,
                    const int* __restrict__ bbase, uint2* __restrict__ spackA) {
  __shared__ int cur[NBUCK];
  const int c = blockIdx.x;
  for (int b = threadIdx.x; b < NBUCK; b += 256)
    cur[b] = bbase[b] + cnt[c * NBUCK + b];
  __syncthreads();
  const int e0 = c * EPC, e1 = e0 + EPC;
  for (int i = e0 + threadIdx.x; i < e1; i += 256) {
    int r = erows[i];
    int p = atomicAdd(&cur[r >> 6], 1);
    uint2 rec;
    rec.x = (unsigned)ecols[i] | ((unsigned)(r & 63) << 17);
    rec.y = __float_as_uint(evals[i]);
    spackA[p] = rec;
  }
}

// -- in-bucket counting sort by rowlow: spackA -> spackB (row-sorted) + row_ptr
__global__ __launch_bounds__(256)
void bucket_sort(const int* __restrict__ bbase, const uint2* __restrict__ spackA,
                 uint2* __restrict__ spackB, int* __restrict__ row_ptr) {
  __shared__ int hist[64];
  __shared__ int hcur[64];
  const int b = blockIdx.x;
  const int tid = threadIdx.x;
  const int j0 = bbase[b], j1 = bbase[b + 1];
  if (tid < 64) hist[tid] = 0;
  __syncthreads();
  for (int k = j0 + tid; k < j1; k += 256)
    atomicAdd(&hist[(spackA[k].x >> 17) & 63], 1);
  __syncthreads();
  if (tid == 0) {
    int s = 0, row0 = b * 64;
    for (int r = 0; r < 64; ++r) {
      int v = hist[r];
      hcur[r] = s;
      if (row0 + r < N_NODES) row_ptr[row0 + r] = j0 + s;
      s += v;
    }
    if (b == NBUCK - 1) row_ptr[N_NODES] = NNZ;
  }
  __syncthreads();
  for (int k = j0 + tid; k < j1; k += 256) {
    uint2 rec = spackA[k];
    int rl = (rec.x >> 17) & 63;
    int p = j0 + atomicAdd(&hcur[rl], 1);
    spackB[p] = rec;
  }
}

// ---------------- SpMM (CSR, fp8 gather): one wave per row ------------------
// DIN=128: whole wave per edge (128B line). DIN=64: dual-edge — each
// half-wave (32 lanes x 2B = 64B row) takes alternate edges, shfl-merge.
template<int DIN>
__global__ __launch_bounds__(256)
void spmm_fp8(const unsigned char* __restrict__ qtab, float inv_scale,
              const int* __restrict__ row_ptr,
              const uint2* __restrict__ spack,
              unsigned short* __restrict__ side) {
  int row  = blockIdx.x * 4 + (threadIdx.x >> 6);
  int lane = threadIdx.x & 63;
  if (row >= N_NODES) return;
  int j0 = row_ptr[row], j1 = row_ptr[row + 1];
  if constexpr (DIN == 128) {
    float ax = 0.f, ay = 0.f;
    #pragma unroll 8
    for (int j = j0; j < j1; ++j) {
      uint2 rec = spack[j];
      float v = __uint_as_float(rec.y);
      unsigned q = *reinterpret_cast<const unsigned short*>(
          qtab + (size_t)(rec.x & 0x1FFFF) * 128 + lane * 2);
      f32x2 xy = __builtin_amdgcn_cvt_pk_f32_fp8(q, false);
      ax += v * xy.x;  ay += v * xy.y;
    }
    *reinterpret_cast<unsigned*>(side + (size_t)row * 128 + lane * 2) =
        pack2(ax * inv_scale, ay * inv_scale);
  } else {
    const int half = lane >> 5;            // 0 or 1: which edge parity
    const int hl   = lane & 31;            // lane within half-wave
    float ax = 0.f, ay = 0.f;
    #pragma unroll 8
    for (int j = j0 + half; j < j1; j += 2) {
      uint2 rec = spack[j];
      float v = __uint_as_float(rec.y);
      unsigned q = *reinterpret_cast<const unsigned short*>(
          qtab + (size_t)(rec.x & 0x1FFFF) * 64 + hl * 2);
      f32x2 xy = __builtin_amdgcn_cvt_pk_f32_fp8(q, false);
      ax += v * xy.x;  ay += v * xy.y;
    }
    ax += __shfl_xor(ax, 32);
    ay += __shfl_xor(ay, 32);
    if (lane < 32)
      *reinterpret_cast<unsigned*>(side + (size_t)row * 64 + hl * 2) =
          pack2(ax * inv_scale, ay * inv_scale);
  }
}

// -------- bi-interaction via MFMA: out = lrelu((e+s)W1+b1)+lrelu((e*s)W2+b2)
template<int DIN, int DOUT, int WM, int WN, int TPB, bool QOUT>
__global__ __launch_bounds__(256)
void bi_mfma(const unsigned short* __restrict__ ego,
             const unsigned short* __restrict__ side,
             const unsigned short* __restrict__ W1t, const float* __restrict__ b1,
             const unsigned short* __restrict__ W2t, const float* __restrict__ b2,
             unsigned short* __restrict__ out,
             unsigned char* __restrict__ outq, float qs) {
  static_assert(WM * WN == 4, "4 waves");
  constexpr int KFRAG = DIN / 32;
  constexpr int NCOLS = DOUT / WN;
  constexpr int NFRAG = NCOLS / 16;
  constexpr int MROWS = 32 / WM;
  constexpr int MFRAG = MROWS / 16;
  constexpr int CPR   = DIN / 8;
  constexpr int CHUNKS = 32 * CPR;

  __shared__ __align__(16) unsigned short lds1[32 * DIN];
  __shared__ __align__(16) unsigned short lds2[32 * DIN];

  const int tid  = threadIdx.x;
  const int wid  = tid >> 6;
  const int lane = tid & 63;
  const int n0   = (wid % WN) * NCOLS;
  const int mrow0 = (wid / WN) * MROWS;
  const int lr   = lane & 15;
  const int lk   = (lane >> 4) * 8;

  bf16x8 w1f[KFRAG][NFRAG], w2f[KFRAG][NFRAG];
  #pragma unroll
  for (int kf = 0; kf < KFRAG; ++kf)
    #pragma unroll
    for (int nf = 0; nf < NFRAG; ++nf) {
      int col = n0 + nf * 16 + lr;
      int kr  = kf * 32 + lk;
      w1f[kf][nf] = *reinterpret_cast<const bf16x8*>(W1t + (size_t)col * DIN + kr);
      w2f[kf][nf] = *reinterpret_cast<const bf16x8*>(W2t + (size_t)col * DIN + kr);
    }
  float b1v[NFRAG], b2v[NFRAG];
  #pragma unroll
  for (int nf = 0; nf < NFRAG; ++nf) {
    b1v[nf] = b1[n0 + nf * 16 + lr];
    b2v[nf] = b2[n0 + nf * 16 + lr];
  }

  for (int t = 0; t < TPB; ++t) {
    int row0 = (blockIdx.x * TPB + t) * 32;
    if (row0 >= N_NODES) break;
    __syncthreads();
    for (int ci = tid; ci < CHUNKS; ci += 256) {
      int r  = ci / CPR;
      int c8 = ci % CPR;
      size_t g = (size_t)(row0 + r) * DIN + c8 * 8;
      uint4 e4 = *reinterpret_cast<const uint4*>(ego + g);
      uint4 s4 = *reinterpret_cast<const uint4*>(side + g);
      uint4 h1v, h2v;
      {
        float ex, ey, sx, sy;
        ex = bf2f((unsigned short)(e4.x & 0xFFFFu)); ey = bf2f((unsigned short)(e4.x >> 16));
        sx = bf2f((unsigned short)(s4.x & 0xFFFFu)); sy = bf2f((unsigned short)(s4.x >> 16));
        h1v.x = pack2(ex + sx, ey + sy); h2v.x = pack2(ex * sx, ey * sy);
        ex = bf2f((unsigned short)(e4.y & 0xFFFFu)); ey = bf2f((unsigned short)(e4.y >> 16));
        sx = bf2f((unsigned short)(s4.y & 0xFFFFu)); sy = bf2f((unsigned short)(s4.y >> 16));
        h1v.y = pack2(ex + sx, ey + sy); h2v.y = pack2(ex * sx, ey * sy);
        ex = bf2f((unsigned short)(e4.z & 0xFFFFu)); ey = bf2f((unsigned short)(e4.z >> 16));
        sx = bf2f((unsigned short)(s4.z & 0xFFFFu)); sy = bf2f((unsigned short)(s4.z >> 16));
        h1v.z = pack2(ex + sx, ey + sy); h2v.z = pack2(ex * sx, ey * sy);
        ex = bf2f((unsigned short)(e4.w & 0xFFFFu)); ey = bf2f((unsigned short)(e4.w >> 16));
        sx = bf2f((unsigned short)(s4.w & 0xFFFFu)); sy = bf2f((unsigned short)(s4.w >> 16));
        h1v.w = pack2(ex + sx, ey + sy); h2v.w = pack2(ex * sx, ey * sy);
      }
      unsigned byte = ((unsigned)(r * DIN + c8 * 8)) * 2u;
      byte ^= (unsigned)((r & 7) << 4);
      *reinterpret_cast<uint4*>(reinterpret_cast<char*>(lds1) + byte) = h1v;
      *reinterpret_cast<uint4*>(reinterpret_cast<char*>(lds2) + byte) = h2v;
    }
    __syncthreads();

    f32x4 acc1[MFRAG][NFRAG], acc2[MFRAG][NFRAG];
    #pragma unroll
    for (int mf = 0; mf < MFRAG; ++mf)
      #pragma unroll
      for (int nf = 0; nf < NFRAG; ++nf) {
        acc1[mf][nf] = (f32x4)0.f;
        acc2[mf][nf] = (f32x4)0.f;
      }
    #pragma unroll
    for (int kf = 0; kf < KFRAG; ++kf) {
      bf16x8 a1[MFRAG], a2[MFRAG];
      #pragma unroll
      for (int mf = 0; mf < MFRAG; ++mf) {
        int r = mrow0 + mf * 16 + lr;
        unsigned byte = ((unsigned)(r * DIN + kf * 32 + lk)) * 2u;
        byte ^= (unsigned)((r & 7) << 4);
        a1[mf] = *reinterpret_cast<const bf16x8*>(reinterpret_cast<const char*>(lds1) + byte);
        a2[mf] = *reinterpret_cast<const bf16x8*>(reinterpret_cast<const char*>(lds2) + byte);
      }
      #pragma unroll
      for (int mf = 0; mf < MFRAG; ++mf)
        #pragma unroll
        for (int nf = 0; nf < NFRAG; ++nf) {
          acc1[mf][nf] = __builtin_amdgcn_mfma_f32_16x16x32_bf16(a1[mf], w1f[kf][nf], acc1[mf][nf], 0, 0, 0);
          acc2[mf][nf] = __builtin_amdgcn_mfma_f32_16x16x32_bf16(a2[mf], w2f[kf][nf], acc2[mf][nf], 0, 0, 0);
        }
    }

    #pragma unroll
    for (int mf = 0; mf < MFRAG; ++mf)
      #pragma unroll
      for (int nf = 0; nf < NFRAG; ++nf) {
        #pragma unroll
        for (int reg = 0; reg < 4; ++reg) {
          int r = row0 + mrow0 + mf * 16 + (lane >> 4) * 4 + reg;
          int c = n0 + nf * 16 + lr;
          float o = lrelu(acc1[mf][nf][reg] + b1v[nf]) + lrelu(acc2[mf][nf][reg] + b2v[nf]);
          out[(size_t)r * DOUT + c] = f2bf(o);
          if constexpr (QOUT) {
            float oq = o * qs;
            outq[(size_t)r * DOUT + c] =
                (unsigned char)(__builtin_amdgcn_cvt_pk_fp8_f32(oq, oq, 0, false) & 0xFF);
          }
        }
      }
  }
}

// -------- fused score pass over all 4 layer outputs -------------------------
__global__ __launch_bounds__(256)
void score_all(const float* __restrict__ emb0,
               const unsigned short* __restrict__ e1,
               const unsigned short* __restrict__ e2,
               const unsigned short* __restrict__ e3,
               const int* __restrict__ uid, const int* __restrict__ pid,
               const int* __restrict__ nid,
               float* __restrict__ pos, float* __restrict__ neg,
               float* __restrict__ l2) {
  int i = blockIdx.x * 4 + (threadIdx.x >> 6);
  int lane = threadIdx.x & 63;
  if (i >= CFB) return;
  const int ui = uid[i], pi = pid[i], gi = nid[i];
  float PS = 0.f, NS = 0.f, L2 = 0.f;

  {
    float up = 0, un = 0, uu = 0, pp = 0, nn = 0;
    for (int d = lane; d < 128; d += 64) {
      float a = emb0[(size_t)ui * 128 + d];
      float b = emb0[(size_t)pi * 128 + d];
      float c = emb0[(size_t)gi * 128 + d];
      up += a * b; un += a * c; uu += a * a; pp += b * b; nn += c * c;
    }
    #pragma unroll
    for (int off = 32; off > 0; off >>= 1) {
      up += __shfl_xor(up, off); un += __shfl_xor(un, off);
      uu += __shfl_xor(uu, off); pp += __shfl_xor(pp, off); nn += __shfl_xor(nn, off);
    }
    PS += up; NS += un; L2 += uu + pp + nn;
  }
  const unsigned short* tabs[3] = { e1, e2, e3 };
  const int dims[3] = { 128, 64, 32 };
  #pragma unroll
  for (int L = 0; L < 3; ++L) {
    const unsigned short* T = tabs[L];
    const int dim = dims[L];
    float up = 0, un = 0, uu = 0, pp = 0, nn = 0;
    for (int d = lane; d < dim; d += 64) {
      float a = bf2f(T[(size_t)ui * dim + d]);
      float b = bf2f(T[(size_t)pi * dim + d]);
      float c = bf2f(T[(size_t)gi * dim + d]);
      up += a * b; un += a * c; uu += a * a; pp += b * b; nn += c * c;
    }
    #pragma unroll
    for (int off = 32; off > 0; off >>= 1) {
      up += __shfl_xor(up, off); un += __shfl_xor(un, off);
      uu += __shfl_xor(uu, off); pp += __shfl_xor(pp, off); nn += __shfl_xor(nn, off);
    }
    float mu = fmaxf(sqrtf(uu), 1e-12f);
    float mp = fmaxf(sqrtf(pp), 1e-12f);
    float mn = fmaxf(sqrtf(nn), 1e-12f);
    PS += up / (mu * mp);
    NS += un / (mu * mn);
    L2 += uu / (mu * mu) + pp / (mp * mp) + nn / (mn * mn);
  }
  if (lane == 0) { pos[i] = PS; neg[i] = NS; l2[i] = L2; }
}

// ---------------------------- final loss reduce -----------------------------
__global__ __launch_bounds__(256)
void loss_kernel(const float* __restrict__ pos, const float* __restrict__ neg,
                 const float* __restrict__ l2, float* __restrict__ out) {
  __shared__ float s1[256];
  __shared__ float s2[256];
  int tid = threadIdx.x;
  float cf = 0.f, reg = 0.f;
  for (int i = tid; i < CFB; i += 256) {
    float x = pos[i] - neg[i];
    float sp = (x > 0.f) ? log1pf(expf(-x)) : (-x + log1pf(expf(x)));
    cf  += sp;
    reg += l2[i];
  }
  s1[tid] = cf; s2[tid] = reg;
  __syncthreads();
  for (int s = 128; s > 0; s >>= 1) {
    if (tid < s) { s1[tid] += s1[tid + s]; s2[tid] += s2[tid + s]; }
    __syncthreads();
  }
  if (tid == 0)
    out[0] = s1[0] / (float)CFB + 1e-5f * (0.5f * s2[0] / (float)CFB);
}

extern "C" void kernel_launch(void* const* d_in, const int* in_sizes, int n_in,
                              void* d_out, int out_size, void* d_ws, size_t ws_size,
                              hipStream_t stream) {
  const float* embed = (const float*)d_in[0];
  const float* W1_0 = (const float*)d_in[1];
  const float* b1_0 = (const float*)d_in[2];
  const float* W2_0 = (const float*)d_in[3];
  const float* b2_0 = (const float*)d_in[4];
  const float* W1_1 = (const float*)d_in[5];
  const float* b1_1 = (const float*)d_in[6];
  const float* W2_1 = (const float*)d_in[7];
  const float* b2_1 = (const float*)d_in[8];
  const float* W1_2 = (const float*)d_in[9];
  const float* b1_2 = (const float*)d_in[10];
  const float* W2_2 = (const float*)d_in[11];
  const float* b2_2 = (const float*)d_in[12];
  const int*   erows = (const int*)d_in[13];
  const int*   ecols = (const int*)d_in[14];
  const float* evals = (const float*)d_in[15];
  const int*   uid = (const int*)d_in[16];
  const int*   pid = (const int*)d_in[17];
  const int*   nid = (const int*)d_in[18];

  // ---------------- workspace layout (~146 MB) ----------------
  unsigned short* e0 = (unsigned short*)d_ws;               // N*128 bf16
  unsigned short* e1 = e0 + (size_t)N_NODES * 128;          // N*128
  unsigned short* e2 = e1 + (size_t)N_NODES * 128;          // N*64
  unsigned short* e3 = e2 + (size_t)N_NODES * 64;           // N*32
  unsigned short* sb = e3 + (size_t)N_NODES * 32;           // N*128 (side)
  unsigned char*  q0 = (unsigned char*)(sb + (size_t)N_NODES * 128);  // N*128 fp8
  unsigned char*  q2 = q0 + (size_t)N_NODES * 128;          // N*64 fp8
  unsigned short* wt = (unsigned short*)(q2 + (size_t)N_NODES * 64);  // WTOT bf16
  int*   cnt     = (int*)(wt + WTOT);                       // NE (chunk x bucket)
  int*   btot    = cnt + NE;                                // NBUCK
  int*   bbase   = btot + NBUCK;                            // NBUCK+1
  int*   row_ptr = bbase + NBUCK + 1;                       // N+1
  uint2* spackA  = (uint2*)(row_ptr + N_NODES + 2);         // NNZ (dead after build)
  uint2* spackB  = spackA + NNZ;                            // NNZ
  unsigned char* q1 = (unsigned char*)spackA;               // N*128 fp8 (aliases spackA)
  float* posb    = (float*)(spackB + NNZ);
  float* negb    = posb + CFB;
  float* l2b     = negb + CFB;

  // ---------------- fused prep + CSR build ----------------
  cvt_fused<<<NCHUNK, 256, 0, stream>>>(embed, e0, q0, W1_0, W2_0, W1_1, W2_1,
                                        W1_2, W2_2, wt, erows, cnt);
  bucket_scan<<<NBUCK, NCHUNK, 0, stream>>>(cnt, btot);
  base_scan<<<1, 256, 0, stream>>>(btot, bbase);
  scatter_bucket<<<NCHUNK, 256, 0, stream>>>(erows, ecols, evals, cnt, bbase, spackA);
  bucket_sort<<<NBUCK, 256, 0, stream>>>(bbase, spackA, spackB, row_ptr);

  constexpr int TPB = 5;
  constexpr int GB  = (N_NODES / 32 + TPB - 1) / TPB;

  // ---- layer 0: 128 -> 128 (gather fp8 q0, scale 1024) ----
  spmm_fp8<128><<<(N_NODES + 3) / 4, 256, 0, stream>>>(q0, 1.f / 1024.f, row_ptr, spackB, sb);
  bi_mfma<128, 128, 1, 4, TPB, true><<<GB, 256, 0, stream>>>(e0, sb, wt + WOF_10, b1_0, wt + WOF_20, b2_0, e1, q1, 64.f);

  // ---- layer 1: 128 -> 64 (gather fp8 q1, scale 64) ----
  spmm_fp8<128><<<(N_NODES + 3) / 4, 256, 0, stream>>>(q1, 1.f / 64.f, row_ptr, spackB, sb);
  bi_mfma<128, 64, 1, 4, TPB, true><<<GB, 256, 0, stream>>>(e1, sb, wt + WOF_11, b1_1, wt + WOF_21, b2_1, e2, q2, 64.f);

  // ---- layer 2: 64 -> 32 (gather fp8 q2, scale 64, dual-edge waves) ----
  spmm_fp8<64><<<(N_NODES + 3) / 4, 256, 0, stream>>>(q2, 1.f / 64.f, row_ptr, spackB, sb);
  bi_mfma<64, 32, 2, 2, TPB, false><<<GB, 256, 0, stream>>>(e2, sb, wt + WOF_12, b1_2, wt + WOF_22, b2_2, e3, (unsigned char*)nullptr, 0.f);

  // ---- fused scoring over all 4 layer outputs + loss ----
  score_all<<<CFB / 4, 256, 0, stream>>>(embed, e1, e2, e3, uid, pid, nid, posb, negb, l2b);
  loss_kernel<<<1, 256, 0, stream>>>(posb, negb, l2b, (float*)d_out);
}